// Round 6
// baseline (460.424 us; speedup 1.0000x reference)
//
#include <hip/hip_runtime.h>

// ============================================================================
// ExplicitSVDBlock round 6:
//  - GEMMs (gemm_bt, gemm_bt64, qkv2): 3-stage LDS pipeline with
//    s_waitcnt vmcnt(N!=0) + raw s_barrier (AITER-style). Tile k+2 staged at
//    iter k; barrier waits only for tile k+1 (leaves newest stage in flight).
//  - attention / prep / ln unchanged from round 5.
// ============================================================================

typedef unsigned short u16;
typedef unsigned int u32;
typedef u16 u16x8 __attribute__((ext_vector_type(8)));
typedef __bf16 bf16x8 __attribute__((ext_vector_type(8)));
typedef float f32x4 __attribute__((ext_vector_type(4)));

__device__ __forceinline__ u16 f2bf(float f) {
    u32 u = __builtin_bit_cast(u32, f);
    u += 0x7fff + ((u >> 16) & 1);          // RNE
    return (u16)(u >> 16);
}
__device__ __forceinline__ float bf2f(u16 h) {
    u32 u = ((u32)h) << 16;
    return __builtin_bit_cast(float, u);
}
// pack trunc-bf16(a) into low16, trunc-bf16(b) into high16 (one v_perm_b32)
__device__ __forceinline__ u32 packbf(float a, float b) {
    return __builtin_amdgcn_perm(__builtin_bit_cast(u32, b),
                                 __builtin_bit_cast(u32, a), 0x07060302u);
}

__device__ __forceinline__ void gload16(const void* g, void* l) {
    __builtin_amdgcn_global_load_lds(
        (const __attribute__((address_space(1))) void*)g,
        (__attribute__((address_space(3))) void*)l, 16, 0, 0);
}

// barrier that waits for all but the newest N in-flight global_load_lds
#define PIPE_BARRIER(N) __asm__ volatile(                         \
    "s_waitcnt vmcnt(" #N ") lgkmcnt(0)\n\ts_barrier" ::: "memory")

// ---------------------------------------------------------------------------
// Workspace layout. Total 109 MB.
// ---------------------------------------------------------------------------
#define MB 1048576u
#define OFF_UQKVT (0*MB)    // bf16 [1536][1024]
#define OFF_VQKVT (3*MB)    // bf16 [3][1024][512]
#define OFF_WOB   (6*MB)    // bf16 [1024][1024]
#define OFF_U1T   (8*MB)    // bf16 [1024][1024]
#define OFF_V1TP  (10*MB)   // bf16 [4096][1024]  col-interleaved for geglu
#define OFF_U2T   (18*MB)   // bf16 [1024][2048]
#define OFF_V2T   (22*MB)   // bf16 [1024][1024]
#define OFF_BQKV  (24*MB)   // f32 [3][1024]; +16KB: b1p f32 [4096]
#define OFF_B1P   (24*MB + 16384u)
#define OFF_XN    (25*MB)   // bf16 [4096][1024]
#define OFF_TBUF  (33*MB)   // bf16 [4096][1536]
#define OFF_QB    (45*MB)   // bf16 [4096][1024] (q) -- dead after attn
#define OFF_KB    (53*MB)   // bf16 [4096][1024] (k) -- dead after attn
#define OFF_HB    (45*MB)   // bf16 [4096][2048] (h; reuses q/k space)
#define OFF_VTB   (61*MB)   // bf16 [32][64][2048]
#define OFF_OB    (69*MB)   // bf16 [4096][1024]
#define OFF_X2    (93*MB)   // f32  [4096][1024]

// ---------------------------------------------------------------------------
// Fused weight prep (single launch, block-range dispatch). Grid = 12304.
// ---------------------------------------------------------------------------
__global__ __launch_bounds__(256) void prep_kernel(
    const float* __restrict__ Uq, const float* __restrict__ Uk,
    const float* __restrict__ Uv, const float* __restrict__ Vq,
    const float* __restrict__ Vk, const float* __restrict__ Vv,
    const float* __restrict__ Wo, const float* __restrict__ U1,
    const float* __restrict__ V1, const float* __restrict__ U2,
    const float* __restrict__ V2,
    const float* __restrict__ bq, const float* __restrict__ bk,
    const float* __restrict__ bv, const float* __restrict__ b1,
    u16* __restrict__ UQKVT, u16* __restrict__ VQKVT, u16* __restrict__ WOB,
    u16* __restrict__ U1T, u16* __restrict__ V1TP, u16* __restrict__ U2T,
    u16* __restrict__ V2T, float* __restrict__ BQKV, float* __restrict__ B1P)
{
    __shared__ float tile[32][33];
    int bid = blockIdx.x;

    if (bid >= 12288) {            // biascat
        int id = (bid - 12288) * 256 + threadIdx.x;   // 0..4095
        if (id < 3072) {
            float v = (id < 1024) ? bq[id] : (id < 2048 ? bk[id - 1024] : bv[id - 2048]);
            BQKV[id] = v;
        }
        int g = id >> 5, s = id & 31;
        B1P[id] = b1[(s < 16) ? (g*16 + s) : (2048 + g*16 + (s - 16))];
        return;
    }
    if (bid >= 11264) {            // Wo convert
        int i4 = ((bid - 11264) * 256 + threadIdx.x) * 4;
        float4 v = *(const float4*)(Wo + i4);
        u16 tmp[4] = {f2bf(v.x), f2bf(v.y), f2bf(v.z), f2bf(v.w)};
        *(uint2*)(WOB + i4) = *(const uint2*)tmp;
        return;
    }

    const float* src; u16* dst; int K, N, src_ld, nx; bool gg = false;
    if (bid < 3072) {
        int t = bid / 512; bid -= t * 512;
        if (t < 3) { src = t==0 ? Uq : (t==1 ? Uk : Uv);
                     dst = UQKVT + t * 512*1024; K = 1024; N = 512; src_ld = 512; nx = 16; }
        else { int z = t - 3; src = z==0 ? Vq : (z==1 ? Vk : Vv);
               dst = VQKVT + z * 524288; K = 512; N = 1024; src_ld = 1024; nx = 32; }
    } else if (bid < 4096)  { src = U1; dst = U1T;  K = 1024; N = 1024; src_ld = 1024; nx = 32;  bid -= 3072; }
    else if (bid < 8192)    { src = V1; dst = V1TP; K = 1024; N = 4096; src_ld = 4096; nx = 128; bid -= 4096; gg = true; }
    else if (bid < 10240)   { src = U2; dst = U2T;  K = 2048; N = 1024; src_ld = 1024; nx = 32;  bid -= 8192; }
    else                    { src = V2; dst = V2T;  K = 1024; N = 1024; src_ld = 1024; nx = 32;  bid -= 10240; }

    int tx = threadIdx.x & 31, ty = threadIdx.x >> 5;
    int n0 = (bid % nx) * 32, k0 = (bid / nx) * 32;
    int srccol;
    if (gg) { int g = n0 >> 5; srccol = (tx < 16) ? (g*16 + tx) : (2048 + g*16 + (tx - 16)); }
    else srccol = n0 + tx;
    for (int i = 0; i < 4; i++)
        tile[ty + i*8][tx] = src[(size_t)(k0 + ty + i*8) * src_ld + srccol];
    __syncthreads();
    for (int i = 0; i < 4; i++)
        dst[(size_t)(n0 + ty + i*8) * K + k0 + tx] = f2bf(tile[tx][ty + i*8]);
}

// ---------------------------------------------------------------------------
// LayerNorm
// ---------------------------------------------------------------------------
__global__ __launch_bounds__(256) void ln_kernel(
    const float* __restrict__ x, const float* __restrict__ g,
    const float* __restrict__ bta, u16* __restrict__ out)
{
    int w = threadIdx.x >> 6, lane = threadIdx.x & 63;
    int row = blockIdx.x * 4 + w;
    const float* xr = x + (size_t)row * 1024;
    float vals[16];
    float s = 0.f, s2 = 0.f;
    #pragma unroll
    for (int ii = 0; ii < 16; ii++) {
        float v = xr[lane + ii*64];
        vals[ii] = v; s += v; s2 += v * v;
    }
    #pragma unroll
    for (int off = 1; off < 64; off <<= 1) {
        s  += __shfl_xor(s, off);
        s2 += __shfl_xor(s2, off);
    }
    float mu = s * (1.f/1024.f);
    float var = s2 * (1.f/1024.f) - mu * mu;
    float rs = rsqrtf(var + 1e-5f);
    #pragma unroll
    for (int ii = 0; ii < 16; ii++) {
        int col = lane + ii*64;
        out[(size_t)row * 1024 + col] = f2bf((vals[ii] - mu) * rs * g[col] + bta[col]);
    }
}

// ---------------------------------------------------------------------------
// Pipelined GEMM, 128x128 tile, 3-stage (used by V1-geglu).
// mode 0: f32 out + bias + resid; 1: bf16 out (+bias); 2: geglu bf16 out
// ---------------------------------------------------------------------------
__global__ __launch_bounds__(256) void gemm_bt_kernel(
    const u16* __restrict__ A, int lda, const u16* __restrict__ Bt,
    void* __restrict__ Cout, int ldc, const float* __restrict__ bias,
    const float* __restrict__ resid, int Kdim, int mode)
{
    __shared__ u16 As[3][4096];
    __shared__ u16 Bs[3][4096];
    int tid = threadIdx.x;
    int m0 = blockIdx.y * 128, n0 = blockIdx.x * 128;
    int w = tid >> 6, lane = tid & 63, quad = lane >> 4, l15 = lane & 15;
    int wm = (w >> 1) * 64, wn = (w & 1) * 64;
    int sr = tid >> 2, sc8 = (tid & 3) * 8;

    f32x4 acc[4][4] = {};

    const u16* Ap = A  + (size_t)(m0 + sr) * lda  + sc8;
    const u16* Bp = Bt + (size_t)(n0 + sr) * Kdim + sc8;

    #define GSTAGE(buf, koff) do {                                        \
        gload16(Ap + (koff),                     &As[buf][tid * 8]);      \
        gload16(Ap + (koff) + (size_t)64 * lda,  &As[buf][2048 + tid*8]); \
        gload16(Bp + (koff),                     &Bs[buf][tid * 8]);      \
        gload16(Bp + (koff) + (size_t)64 * Kdim, &Bs[buf][2048 + tid*8]); \
    } while (0)

    GSTAGE(0, 0);
    GSTAGE(1, 32);
    PIPE_BARRIER(4);                     // tile 0 landed; tile 1 in flight

    int kt = 0;
    for (int k0 = 0; k0 < Kdim; k0 += 32, kt++) {
        int cur = kt % 3;
        bool st = (k0 + 64) < Kdim;
        if (st) GSTAGE((kt + 2) % 3, k0 + 64);
        const u16* Asc = As[cur];
        const u16* Bsc = Bs[cur];
        bf16x8 af[4], bfr[4];
        #pragma unroll
        for (int i = 0; i < 4; i++)
            af[i] = *(const bf16x8*)&Asc[(wm + i*16 + l15) * 32 + quad * 8];
        #pragma unroll
        for (int j = 0; j < 4; j++)
            bfr[j] = *(const bf16x8*)&Bsc[(wn + j*16 + l15) * 32 + quad * 8];
        #pragma unroll
        for (int i = 0; i < 4; i++)
            #pragma unroll
            for (int j = 0; j < 4; j++)
                acc[i][j] = __builtin_amdgcn_mfma_f32_16x16x32_bf16(af[i], bfr[j], acc[i][j], 0, 0, 0);
        if (k0 + 32 < Kdim) {
            if (st) PIPE_BARRIER(4);     // wait tile k+1; leave k+2 in flight
            else    PIPE_BARRIER(0);     // tail: drain
        }
    }
    #undef GSTAGE

    if (mode == 2) {
        u16* hb = (u16*)Cout;
        #pragma unroll
        for (int i = 0; i < 4; i++) {
            int row = m0 + wm + i*16 + quad*4;
            #pragma unroll
            for (int p = 0; p < 2; p++) {
                int colz = n0 + wn + p*32 + l15;
                float bz1 = bias[colz], bz2 = bias[colz + 16];
                int hcol = ((n0 + wn) >> 1) + p*16 + l15;
                #pragma unroll
                for (int r = 0; r < 4; r++) {
                    float z1 = acc[i][2*p][r] + bz1;
                    float z2 = acc[i][2*p+1][r] + bz2;
                    float uu = 0.7978845608028654f * (z1 + 0.044715f * z1 * z1 * z1);
                    float e = __expf(2.f * uu);
                    float th = (e - 1.f) / (e + 1.f);
                    float hv = 0.5f * z1 * (1.f + th) * z2;
                    hb[(size_t)(row + r) * ldc + hcol] = f2bf(hv);
                }
            }
        }
        return;
    }
    #pragma unroll
    for (int i = 0; i < 4; i++) {
        int row = m0 + wm + i*16 + quad*4;
        #pragma unroll
        for (int j = 0; j < 4; j++) {
            int col = n0 + wn + j*16 + l15;
            float bv = bias ? bias[col] : 0.f;
            #pragma unroll
            for (int r = 0; r < 4; r++) {
                float v = acc[i][j][r] + bv;
                size_t idx = (size_t)(row + r) * ldc + col;
                if (mode == 0) ((float*)Cout)[idx] = v + resid[idx];
                else           ((u16*)Cout)[idx] = f2bf(v);
            }
        }
    }
}

// ---------------------------------------------------------------------------
// Pipelined GEMM, 128x64 tile, 3-stage. wave-tile 64x32 (4x2 frags).
// mode 0: f32+bias+resid; 1: bf16 (+bias)
// ---------------------------------------------------------------------------
__global__ __launch_bounds__(256) void gemm_bt64_kernel(
    const u16* __restrict__ A, int lda, const u16* __restrict__ Bt,
    void* __restrict__ Cout, int ldc, const float* __restrict__ bias,
    const float* __restrict__ resid, int Kdim, int mode)
{
    __shared__ u16 As[3][4096];
    __shared__ u16 Bs[3][2048];
    int tid = threadIdx.x;
    int m0 = blockIdx.y * 128, n0 = blockIdx.x * 64;
    int w = tid >> 6, lane = tid & 63, quad = lane >> 4, l15 = lane & 15;
    int wm = (w >> 1) * 64, wn = (w & 1) * 32;
    int sr = tid >> 2, sc8 = (tid & 3) * 8;

    f32x4 acc[4][2] = {};

    const u16* Ap = A  + (size_t)(m0 + sr) * lda  + sc8;
    const u16* Bp = Bt + (size_t)(n0 + sr) * Kdim + sc8;   // sr<64 rows of B

    #define GSTAGE64(buf, koff) do {                                       \
        gload16(Ap + (koff),                     &As[buf][tid * 8]);       \
        gload16(Ap + (koff) + (size_t)64 * lda,  &As[buf][2048 + tid*8]);  \
        gload16(Bp + (koff),                     &Bs[buf][tid * 8]);       \
    } while (0)

    GSTAGE64(0, 0);
    GSTAGE64(1, 32);
    PIPE_BARRIER(3);

    int kt = 0;
    for (int k0 = 0; k0 < Kdim; k0 += 32, kt++) {
        int cur = kt % 3;
        bool st = (k0 + 64) < Kdim;
        if (st) GSTAGE64((kt + 2) % 3, k0 + 64);
        const u16* Asc = As[cur];
        const u16* Bsc = Bs[cur];
        bf16x8 af[4], bfr[2];
        #pragma unroll
        for (int i = 0; i < 4; i++)
            af[i] = *(const bf16x8*)&Asc[(wm + i*16 + l15) * 32 + quad * 8];
        #pragma unroll
        for (int j = 0; j < 2; j++)
            bfr[j] = *(const bf16x8*)&Bsc[(wn + j*16 + l15) * 32 + quad * 8];
        #pragma unroll
        for (int i = 0; i < 4; i++)
            #pragma unroll
            for (int j = 0; j < 2; j++)
                acc[i][j] = __builtin_amdgcn_mfma_f32_16x16x32_bf16(af[i], bfr[j], acc[i][j], 0, 0, 0);
        if (k0 + 32 < Kdim) {
            if (st) PIPE_BARRIER(3);
            else    PIPE_BARRIER(0);
        }
    }
    #undef GSTAGE64

    #pragma unroll
    for (int i = 0; i < 4; i++) {
        int row = m0 + wm + i*16 + quad*4;
        #pragma unroll
        for (int j = 0; j < 2; j++) {
            int col = n0 + wn + j*16 + l15;
            float bv = bias ? bias[col] : 0.f;
            #pragma unroll
            for (int r = 0; r < 4; r++) {
                float v = acc[i][j][r] + bv;
                size_t idx = (size_t)(row + r) * ldc + col;
                if (mode == 0) ((float*)Cout)[idx] = v + resid[idx];
                else           ((u16*)Cout)[idx] = f2bf(v);
            }
        }
    }
}

// ---------------------------------------------------------------------------
// QKV stage-2 batched 3-stage GEMM (z: 0=q(+rope,pre-scale) 1=k(+rope) 2=v^T)
// ---------------------------------------------------------------------------
__global__ __launch_bounds__(256) void qkv2_kernel(
    const u16* __restrict__ T, const u16* __restrict__ Vw,
    const float* __restrict__ bqkv, u16* __restrict__ qout,
    u16* __restrict__ kout, u16* __restrict__ vtout)
{
    __shared__ u16 As[3][4096];
    __shared__ u16 Bs[3][4096];
    int tid = threadIdx.x;
    int z = blockIdx.z;
    int m0 = blockIdx.y * 128, n0 = blockIdx.x * 128;
    int w = tid >> 6, lane = tid & 63, quad = lane >> 4, l15 = lane & 15;
    int wm = (w >> 1) * 64, wn = (w & 1) * 64;
    int sr = tid >> 2, sc8 = (tid & 3) * 8;

    f32x4 acc[4][4] = {};

    const u16* Ap = T  + (size_t)z * 512 + (size_t)(m0 + sr) * 1536 + sc8;
    const u16* Bp = Vw + (size_t)z * 512 * 1024 + (size_t)(n0 + sr) * 512 + sc8;

    #define QSTAGE(buf, koff) do {                                        \
        gload16(Ap + (koff),                     &As[buf][tid * 8]);      \
        gload16(Ap + (koff) + (size_t)64 * 1536, &As[buf][2048 + tid*8]); \
        gload16(Bp + (koff),                     &Bs[buf][tid * 8]);      \
        gload16(Bp + (koff) + (size_t)64 * 512,  &Bs[buf][2048 + tid*8]); \
    } while (0)

    QSTAGE(0, 0);
    QSTAGE(1, 32);
    PIPE_BARRIER(4);

    int kt = 0;
    for (int k0 = 0; k0 < 512; k0 += 32, kt++) {
        int cur = kt % 3;
        bool st = (k0 + 64) < 512;
        if (st) QSTAGE((kt + 2) % 3, k0 + 64);
        const u16* Asc = As[cur];
        const u16* Bsc = Bs[cur];
        bf16x8 af[4], bfr[4];
        #pragma unroll
        for (int i = 0; i < 4; i++)
            af[i] = *(const bf16x8*)&Asc[(wm + i*16 + l15) * 32 + quad * 8];
        #pragma unroll
        for (int j = 0; j < 4; j++)
            bfr[j] = *(const bf16x8*)&Bsc[(wn + j*16 + l15) * 32 + quad * 8];
        #pragma unroll
        for (int i = 0; i < 4; i++)
            #pragma unroll
            for (int j = 0; j < 4; j++)
                acc[i][j] = __builtin_amdgcn_mfma_f32_16x16x32_bf16(af[i], bfr[j], acc[i][j], 0, 0, 0);
        if (k0 + 32 < 512) {
            if (st) PIPE_BARRIER(4);
            else    PIPE_BARRIER(0);
        }
    }
    #undef QSTAGE

    const float* bias = bqkv + z * 1024;
    if (z < 2) {
        u16* Ob = z ? kout : qout;
        float qscale = z ? 1.f : 0.18033688011112042f;   // 0.125*log2(e) folded into q
        #pragma unroll
        for (int i = 0; i < 4; i++) {
            int row0 = m0 + wm + i*16 + quad*4;
            #pragma unroll
            for (int j = 0; j < 2; j++) {
                int col = n0 + wn + j*16 + l15;       // (col&63) < 32
                float bj = bias[col], bj2 = bias[col + 32];
                float invf = exp2f((float)(col & 31) * -0.4152410118609203f);
                #pragma unroll
                for (int r = 0; r < 4; r++) {
                    int t = row0 + r;
                    float fr = (float)(t & 2047) * invf;
                    float sn, cs;
                    __sincosf(fr, &sn, &cs);
                    sn *= qscale; cs *= qscale;
                    float v1 = acc[i][j][r] + bj;
                    float v2 = acc[i][j+2][r] + bj2;
                    Ob[(size_t)t * 1024 + col]      = f2bf(v1 * cs - v2 * sn);
                    Ob[(size_t)t * 1024 + col + 32] = f2bf(v2 * cs + v1 * sn);
                }
            }
        }
    } else {
        int bb = m0 >> 11;
        #pragma unroll
        for (int i = 0; i < 4; i++) {
            int row0 = m0 + wm + i*16 + quad*4;
            #pragma unroll
            for (int j = 0; j < 4; j++) {
                int col = n0 + wn + j*16 + l15;
                float bj = bias[col];
                u16 pack[4];
                #pragma unroll
                for (int r = 0; r < 4; r++) pack[r] = f2bf(acc[i][j][r] + bj);
                size_t dst = ((size_t)(bb * 16 + (col >> 6)) * 64 + (col & 63)) * 2048 + (row0 & 2047);
                *(uint2*)&vtout[dst] = *(const uint2*)pack;
            }
        }
    }
}

// ---------------------------------------------------------------------------
// Flash attention v4 (unchanged): S^T form, packed b64 P-writes, no-max
// softmax (Q pre-scaled by 0.125*log2e), K/V double-buffered.
// ---------------------------------------------------------------------------
__global__ __launch_bounds__(256) void attn_kernel(
    const u16* __restrict__ Q, const u16* __restrict__ K,
    const u16* __restrict__ Vt, u16* __restrict__ O)
{
    __shared__ u16 Ks[2][64 * 64];
    __shared__ u16 Vs[2][64 * 64];
    __shared__ u16 Ps[128 * 72];
    int tid = threadIdx.x;
    int bh = blockIdx.x;
    int b = bh >> 4, h = bh & 15;
    int m0 = blockIdx.y * 128;
    int w = tid >> 6, lane = tid & 63, quad = lane >> 4, l15 = lane & 15;
    int wm = w * 32;
    size_t qkbase = (size_t)b * 2048 * 1024 + h * 64;
    const u16* Vg = Vt + (size_t)bh * 64 * 2048;

    bf16x8 qf[2][2];
    #pragma unroll
    for (int i = 0; i < 2; i++)
        #pragma unroll
        for (int ks = 0; ks < 2; ks++)
            qf[i][ks] = *(const bf16x8*)(Q + qkbase +
                (size_t)(m0 + wm + i*16 + l15) * 1024 + ks*32 + quad*8);

    f32x4 oacc[2][4] = {};
    float lsum[2] = {};     // per-lane partial row-sum for qrow = wm + i*16 + l15

    int r0 = tid >> 3, p = tid & 7;
    int c0 = (p ^ (r0 & 7)) * 8;
    int xsw = l15 & 7;

    #define STAGE(buf, key0) do {                                               \
        gload16(K + qkbase + (size_t)((key0) + r0) * 1024 + c0,                 \
                &Ks[buf][r0 * 64 + p * 8]);                                     \
        gload16(K + qkbase + (size_t)((key0) + r0 + 32) * 1024 + c0,            \
                &Ks[buf][(r0 + 32) * 64 + p * 8]);                              \
        gload16(Vg + (size_t)r0 * 2048 + (key0) + c0,                           \
                &Vs[buf][r0 * 64 + p * 8]);                                     \
        gload16(Vg + (size_t)(r0 + 32) * 2048 + (key0) + c0,                    \
                &Vs[buf][(r0 + 32) * 64 + p * 8]);                              \
    } while (0)

    STAGE(0, 0);
    __syncthreads();

    for (int kt = 0; kt < 32; kt++) {
        int cur = kt & 1;
        if (kt < 31) STAGE(cur ^ 1, (kt + 1) * 64);
        const u16* Ksc = Ks[cur];
        const u16* Vsc = Vs[cur];

        // S^T = K Q^T: sacc[jj][i]; col(l15)=qrow, row(quad*4+r)=key jj*16+quad*4+r
        f32x4 sacc[4][2] = {};
        #pragma unroll
        for (int ks = 0; ks < 2; ks++) {
            bf16x8 kf[4];
            #pragma unroll
            for (int jj = 0; jj < 4; jj++)
                kf[jj] = *(const bf16x8*)&Ksc[(jj*16 + l15) * 64 + (((ks*4 + quad) ^ xsw) * 8)];
            #pragma unroll
            for (int jj = 0; jj < 4; jj++)
                #pragma unroll
                for (int i = 0; i < 2; i++)
                    sacc[jj][i] = __builtin_amdgcn_mfma_f32_16x16x32_bf16(kf[jj], qf[i][ks], sacc[jj][i], 0, 0, 0);
        }

        // p = 2^s; per-lane partials; packed b64 write to Ps[qrow][key]
        #pragma unroll
        for (int i = 0; i < 2; i++) {
            int prow = (wm + i*16 + l15) * 72 + quad*4;
            #pragma unroll
            for (int jj = 0; jj < 4; jj++) {
                float p0 = __builtin_amdgcn_exp2f(sacc[jj][i][0]);
                float p1 = __builtin_amdgcn_exp2f(sacc[jj][i][1]);
                float p2 = __builtin_amdgcn_exp2f(sacc[jj][i][2]);
                float p3 = __builtin_amdgcn_exp2f(sacc[jj][i][3]);
                lsum[i] += (p0 + p1) + (p2 + p3);
                uint2 pk; pk.x = packbf(p0, p1); pk.y = packbf(p2, p3);
                *(uint2*)&Ps[prow + jj*16] = pk;
            }
        }

        // PV: O[qrow][d] += P[qrow][key] * Vt[d][key]^T
        #pragma unroll
        for (int ks = 0; ks < 2; ks++) {
            bf16x8 pf[2], vf[4];
            #pragma unroll
            for (int i = 0; i < 2; i++)
                pf[i] = *(const bf16x8*)&Ps[(wm + i*16 + l15) * 72 + ks*32 + quad*8];
            #pragma unroll
            for (int j = 0; j < 4; j++)
                vf[j] = *(const bf16x8*)&Vsc[(j*16 + l15) * 64 + (((ks*4 + quad) ^ xsw) * 8)];
            #pragma unroll
            for (int i = 0; i < 2; i++)
                #pragma unroll
                for (int j = 0; j < 4; j++)
                    oacc[i][j] = __builtin_amdgcn_mfma_f32_16x16x32_bf16(pf[i], vf[j], oacc[i][j], 0, 0, 0);
        }
        __syncthreads();
    }
    #undef STAGE

    // finalize row sums: reduce across quads, then redistribute to C-layout rows
    float inv[2][4];
    #pragma unroll
    for (int i = 0; i < 2; i++) {
        float s = lsum[i];
        s += __shfl_xor(s, 16);
        s += __shfl_xor(s, 32);
        #pragma unroll
        for (int r = 0; r < 4; r++)
            inv[i][r] = 1.f / __shfl(s, (lane & 48) | (quad*4 + r));
    }
    #pragma unroll
    for (int i = 0; i < 2; i++)
        #pragma unroll
        for (int r = 0; r < 4; r++) {
            int row = m0 + wm + i*16 + quad*4 + r;
            #pragma unroll
            for (int j = 0; j < 4; j++)
                O[qkbase + (size_t)row * 1024 + j*16 + l15] = f2bf(oacc[i][j][r] * inv[i][r]);
        }
}

// ---------------------------------------------------------------------------
// Launch
// ---------------------------------------------------------------------------
extern "C" void kernel_launch(void* const* d_in, const int* in_sizes, int n_in,
                              void* d_out, int out_size, void* d_ws, size_t ws_size,
                              hipStream_t stream) {
    (void)in_sizes; (void)n_in; (void)out_size; (void)ws_size;
    const float* x     = (const float*)d_in[0];
    const float* ln1_g = (const float*)d_in[1];
    const float* ln1_b = (const float*)d_in[2];
    const float* Uq    = (const float*)d_in[3];
    const float* Vq    = (const float*)d_in[4];
    const float* bq    = (const float*)d_in[5];
    const float* Uk    = (const float*)d_in[6];
    const float* Vk    = (const float*)d_in[7];
    const float* bk    = (const float*)d_in[8];
    const float* Uv    = (const float*)d_in[9];
    const float* Vv    = (const float*)d_in[10];
    const float* bv    = (const float*)d_in[11];
    const float* Wo    = (const float*)d_in[12];
    const float* bo    = (const float*)d_in[13];
    const float* ln2_g = (const float*)d_in[14];
    const float* ln2_b = (const float*)d_in[15];
    const float* U1    = (const float*)d_in[16];
    const float* V1    = (const float*)d_in[17];
    const float* b1    = (const float*)d_in[18];
    const float* U2    = (const float*)d_in[19];
    const float* V2    = (const float*)d_in[20];
    const float* b2    = (const float*)d_in[21];
    float* out = (float*)d_out;
    char* ws = (char*)d_ws;

    u16* UQKVT = (u16*)(ws + OFF_UQKVT);
    u16* VQKVT = (u16*)(ws + OFF_VQKVT);
    u16* WOB   = (u16*)(ws + OFF_WOB);
    u16* U1T   = (u16*)(ws + OFF_U1T);
    u16* V1TP  = (u16*)(ws + OFF_V1TP);
    u16* U2T   = (u16*)(ws + OFF_U2T);
    u16* V2T   = (u16*)(ws + OFF_V2T);
    float* BQKV = (float*)(ws + OFF_BQKV);
    float* B1P  = (float*)(ws + OFF_B1P);
    u16* xn  = (u16*)(ws + OFF_XN);
    u16* tbuf= (u16*)(ws + OFF_TBUF);
    u16* qb  = (u16*)(ws + OFF_QB);
    u16* kb  = (u16*)(ws + OFF_KB);
    u16* vtb = (u16*)(ws + OFF_VTB);
    u16* ob  = (u16*)(ws + OFF_OB);
    u16* hb  = (u16*)(ws + OFF_HB);
    float* x2 = (float*)(ws + OFF_X2);

    // ---- all weight prep: single launch ----
    prep_kernel<<<12304, 256, 0, stream>>>(
        Uq, Uk, Uv, Vq, Vk, Vv, Wo, U1, V1, U2, V2, bq, bk, bv, b1,
        UQKVT, VQKVT, WOB, U1T, V1TP, U2T, V2T, BQKV, B1P);

    // ---- LN1 ----
    ln_kernel<<<1024, 256, 0, stream>>>(x, ln1_g, ln1_b, xn);

    // ---- QKV ----
    gemm_bt64_kernel<<<dim3(24, 32), 256, 0, stream>>>(xn, 1024, UQKVT, tbuf, 1536,
                                                       nullptr, nullptr, 1024, 1);
    qkv2_kernel<<<dim3(8, 32, 3), 256, 0, stream>>>(tbuf, VQKVT, BQKV, qb, kb, vtb);

    // ---- attention ----
    attn_kernel<<<dim3(32, 16), 256, 0, stream>>>(qb, kb, vtb, ob);

    // ---- out proj + residual ----
    gemm_bt64_kernel<<<dim3(16, 32), 256, 0, stream>>>(ob, 1024, WOB, x2, 1024,
                                                       bo, x, 1024, 0);
    // ---- LN2 ----
    ln_kernel<<<1024, 256, 0, stream>>>(x2, ln2_g, ln2_b, xn);

    // ---- FFN ----
    gemm_bt64_kernel<<<dim3(16, 32), 256, 0, stream>>>(xn, 1024, U1T, tbuf, 1024,
                                                       nullptr, nullptr, 1024, 1);
    gemm_bt_kernel<<<dim3(32, 32), 256, 0, stream>>>(tbuf, 1024, V1TP, hb, 2048,
                                                     B1P, nullptr, 1024, 2);
    gemm_bt64_kernel<<<dim3(16, 32), 256, 0, stream>>>(hb, 2048, U2T, tbuf, 1024,
                                                       nullptr, nullptr, 2048, 1);
    gemm_bt64_kernel<<<dim3(16, 32), 256, 0, stream>>>(tbuf, 1024, V2T, out, 1024,
                                                       b2, x2, 1024, 0);
}